// Round 12
// baseline (3219.385 us; speedup 1.0000x reference)
//
#include <hip/hip_runtime.h>
#include <hip/hip_bf16.h>

typedef __attribute__((ext_vector_type(8))) short short8;
typedef __attribute__((ext_vector_type(4))) float f32x4;
typedef unsigned long long u64;
typedef unsigned int u32;

#define SQLEN 256
#define BATCH 128
#define HID   1024
#define NCLS  1000

static __device__ __forceinline__ float sigm(float x){ return 1.0f/(1.0f+__expf(-x)); }
static __device__ __forceinline__ float tanhx(float x){ return 2.0f/(1.0f+__expf(-2.0f*x)) - 1.0f; }
static __device__ __forceinline__ short bf16b(float x){
  __hip_bfloat16 h = __float2bfloat16(x);
  return __builtin_bit_cast(short, h);
}
static __device__ __forceinline__ float bf2f(short s){
  return __bfloat162float(__builtin_bit_cast(__hip_bfloat16, s));
}

// ---- prep: cast x [B][S][I] fp32 -> xbf [(s*128+b)][I] bf16 (permuted) ----
__global__ void cast_x_kernel(const float* __restrict__ x, short* __restrict__ xbf){
  int r = blockIdx.x;            // r = s*128 + b
  int s = r >> 7, b = r & 127;
  const float* src = x + ((size_t)b*SQLEN + s)*HID;
  short* dst = xbf + (size_t)r*HID;
  int k = threadIdx.x*4;
  float4 v = *(const float4*)(src + k);
  short4 o; o.x=bf16b(v.x); o.y=bf16b(v.y); o.z=bf16b(v.z); o.w=bf16b(v.w);
  *(short4*)(dst + k) = o;
}

__global__ void cast_w_kernel(const float* __restrict__ src, short* __restrict__ dst){
  int i = (blockIdx.x*256 + threadIdx.x)*4;
  float4 v = *(const float4*)(src + i);
  short4 o; o.x=bf16b(v.x); o.y=bf16b(v.y); o.z=bf16b(v.z); o.w=bf16b(v.w);
  *(short4*)(dst + i) = o;
}

__global__ void bias_kernel(const float* __restrict__ a, const float* __restrict__ b,
                            float* __restrict__ o){
  int i = blockIdx.x*256 + threadIdx.x;
  o[i] = a[i] + b[i];
}

// ---- mega kernel: SPATIAL overlap of gemm and lstm ----
// Blocks 0..511: BYTE-EXACT R1 lstm recurrence + R6's gcnt-gated xw
// prefetch (both proven). Blocks 512..1023: the proven R9 128^2 gemm as a
// 16-round persistent loop; round r produces s=16r..16r+15 (R6 schedule),
// released via agent-scope xw stores + post-barrier gcnt++ (R6-proven for
// in-kernel consumption). Unlike R6-R8 (temporal fusion: gemm work INSIDE
// lstm blocks poisoned the 256-deep latency chain), here the lstm blocks'
// instruction stream is untouched -- contention is only on shared HW.
// DEADLOCK-PROOF CO-RESIDENCY (required: lstm blocks block on gemm output):
//   launch_bounds(256,4) -> VGPR <= 128 -> 4 waves/SIMD fit (512 regs);
//   LDS unioned to 32KB/block -> 4x32=128 <= 160KB; waves 16 <= 32;
//   => exactly 4 blocks/CU x 256 CU = ALL 1024 blocks resident, any
//   placement. Gating degrades to spins, never deadlock. h-flag graph
//   acyclic in t (R1); gcnt only increases; gemm blocks never wait.
__global__ __launch_bounds__(256,4) void mega_kernel(
    const short* __restrict__ xbf, const short* __restrict__ wxh,
    const float* __restrict__ bias, const short* __restrict__ whh,
    short* __restrict__ xw, short* __restrict__ h_all,
    u32* __restrict__ flags, u32* __restrict__ gcnt)
{
  __shared__ __align__(16) char smem_u[32768];   // union: lstm part | gemm As+Bs
  const int bid = (int)blockIdx.x;
  const int tid = threadIdx.x;
  const int lane = tid & 63, wave = tid >> 6;
  const int l15 = lane & 15, quad = lane >> 4;

  if (bid >= 512){
    // ================= gemm path (512 dedicated blocks) =================
    short* As = (short*)smem_u;            // 8 KB [128][32]
    short* Bs = (short*)(smem_u + 8192);   // 8 KB
    const int g = bid - 512;               // 0..511
    const int wm = (wave>>1)*64, wn = (wave&1)*64;
    const int c0 = wave*64 + lane;         // staging slot, rep 0
    const int c1 = c0 + 256;               // rep 1
    // XCD-chunked task map: XCD c owns 2 bm-panels x 32 bn (A hot = 512KB)
    const int local = ((g & 7) << 6) + (g >> 3);   // 0..511, bijective
    const int bn  = local & 31;
    const int bmi = local >> 5;            // 0..15
    const size_t n0 = (size_t)bn*128;

    #pragma unroll 1
    for (int r = 0; r < 16; ++r){
      const int bm = r*16 + bmi;           // s index, ascending rounds
      const size_t r0 = (size_t)bm*128;
      f32x4 acc[4][4];
      #pragma unroll
      for (int m=0;m<4;++m)
        #pragma unroll
        for (int n=0;n<4;++n) acc[m][n] = (f32x4)0.0f;

      #pragma unroll 1
      for (int kk = 0; kk < 32; ++kk){
        const int k0 = kk*32;
        __syncthreads();   // previous iter's LDS reads done
        __builtin_amdgcn_global_load_lds(
            (const void*)(xbf + (r0 + (c0>>2))*HID + k0 + (c0&3)*8),
            (void*)(As + wave*512), 16, 0, 0);
        __builtin_amdgcn_global_load_lds(
            (const void*)(xbf + (r0 + (c1>>2))*HID + k0 + (c1&3)*8),
            (void*)(As + 2048 + wave*512), 16, 0, 0);
        __builtin_amdgcn_global_load_lds(
            (const void*)(wxh + (n0 + (c0>>2))*HID + k0 + (c0&3)*8),
            (void*)(Bs + wave*512), 16, 0, 0);
        __builtin_amdgcn_global_load_lds(
            (const void*)(wxh + (n0 + (c1>>2))*HID + k0 + (c1&3)*8),
            (void*)(Bs + 2048 + wave*512), 16, 0, 0);
        __syncthreads();   // DMA landed (barrier drains vmcnt)
        short8 af[4], bf[4];
        #pragma unroll
        for (int m=0;m<4;++m) af[m] = *(const short8*)(As + (wm + m*16 + l15)*32 + quad*8);
        #pragma unroll
        for (int n=0;n<4;++n) bf[n] = *(const short8*)(Bs + (wn + n*16 + l15)*32 + quad*8);
        #pragma unroll
        for (int m=0;m<4;++m)
          #pragma unroll
          for (int n=0;n<4;++n)
            acc[m][n] = __builtin_amdgcn_mfma_f32_16x16x32_bf16(af[m], bf[n], acc[m][n], 0,0,0);
      }
      // epilogue: agent-scope stores (consumed in-kernel), then release
      #pragma unroll
      for (int n=0;n<4;++n){
        int s = (int)n0 + wn + n*16;
        float bs = bias[s + l15];
        int gg = s >> 10, jgi = (s & 1023) >> 4;
        #pragma unroll
        for (int m=0;m<4;++m){
          #pragma unroll
          for (int rg=0; rg<4; ++rg){
            u32 w0 = (u32)(unsigned short)bf16b(acc[m][n][rg] + bs);
            u32 w1 = __shfl_down(w0, 1);
            u32 w2 = __shfl_down(w0, 2);
            u32 w3 = __shfl_down(w0, 3);
            if ((l15 & 3) == 0){
              u64 pk = (u64)w0 | ((u64)w1<<16) | ((u64)w2<<32) | ((u64)w3<<48);
              int rowin = wm + m*16 + quad*4 + rg;   // batch b 0..127
              __hip_atomic_store(
                (u64*)(xw + (((size_t)bm*64 + jgi)*128 + rowin)*64 + gg*16 + l15),
                pk, __ATOMIC_RELAXED, __HIP_MEMORY_SCOPE_AGENT);
            }
          }
        }
      }
      __syncthreads();   // all waves' xw stores drained (vmcnt0 at barrier)
      if (tid == 0)
        __hip_atomic_fetch_add(gcnt + bm, 1u, __ATOMIC_RELAXED,
                               __HIP_MEMORY_SCOPE_AGENT);
    }
    return;
  }

  // ================= lstm path (blocks 0..511, byte-exact R1 + gcnt gate) =================
  f32x4 (*part)[4][4][64] = reinterpret_cast<f32x4(*)[4][4][64]>(smem_u);  // 32 KB

  const int bg = bid & 7;               // batch group (XCD-local heuristic)
  const int jg = bid >> 3;              // 0..63
  const int b0 = bg*16;
  const int j0 = jg*16;
  const int ks0 = wave*256;

  __builtin_amdgcn_fence(__ATOMIC_ACQUIRE, "agent");  // once: clear stale L2

  // Whh slice, MFMA B-fragment layout (no pinning -- rounds 2/3)
  short8 Bf[4][8];
  #pragma unroll
  for (int g=0; g<4; ++g)
    #pragma unroll
    for (int kit=0; kit<8; ++kit)
      Bf[g][kit] = *(const short8*)(whh + (size_t)(g*1024 + j0 + l15)*HID
                                    + ks0 + kit*32 + quad*8);

  u32* fgrp = flags + bg*64;            // one h-flag per producer block

  // elementwise cell mapping: cell = tid (r 0..15 x jj 0..15)
  const int r  = tid >> 4;
  const int jj = tid & 15;
  const int ln = (r>>2)*16 + jj;        // frag lane of cell
  const int rg = r & 3;                 // frag reg of cell
  float cc = 0.0f;                      // cell state in register

  // gated prefetch of xw for t=0 (gemm round 0 in flight on sibling blocks)
  short xwc[4];
  {
    while (__hip_atomic_load(gcnt + 0, __ATOMIC_RELAXED,
                             __HIP_MEMORY_SCOPE_AGENT) < 32u)
      __builtin_amdgcn_s_sleep(1);
    asm volatile("" ::: "memory");
    const short* xb = xw + (((size_t)0*64 + jg)*128 + b0 + r)*64 + jj;
    #pragma unroll
    for (int g=0; g<4; ++g) xwc[g] = xb[g*16];
  }

  for (int t = 0; t < SQLEN; ++t){
    const short* hin  = h_all + (size_t)t*131072;
    short*       hout = h_all + (size_t)(t+1)*131072;

    // gated early prefetch of next step's xw (one satisfied poll + load
    // once production leads; R6-proven mechanism)
    short xwn[4];
    if (t < SQLEN-1){
      while (__hip_atomic_load(gcnt + (t+1), __ATOMIC_RELAXED,
                               __HIP_MEMORY_SCOPE_AGENT) < 32u)
        __builtin_amdgcn_s_sleep(1);
      asm volatile("" ::: "memory");
      const short* xb = xw + (((size_t)(t+1)*64 + jg)*128 + b0 + r)*64 + jj;
      #pragma unroll
      for (int g=0; g<4; ++g) xwn[g] = xb[g*16];
    }

    // per-wave spin: the 16 producer blocks of THIS wave's K-slice
    if (t){
      u32* fp = fgrp + wave*16 + l15;
      while (__hip_atomic_load(fp, __ATOMIC_RELAXED,
                               __HIP_MEMORY_SCOPE_AGENT) < (u32)t)
        __builtin_amdgcn_s_sleep(1);
      asm volatile("" ::: "memory");    // no hoist of h loads above the spin
    }

    // h fragments: plain cached coalesced 16B loads (fresh addresses)
    short8 Af[8];
    #pragma unroll
    for (int kit=0; kit<8; ++kit)
      Af[kit] = *(const short8*)(hin + (size_t)(b0 + l15)*HID
                                 + ks0 + kit*32 + quad*8);

    f32x4 acc[4];
    #pragma unroll
    for (int g=0; g<4; ++g) acc[g] = (f32x4)0.0f;
    #pragma unroll
    for (int kit=0; kit<8; ++kit)
      #pragma unroll
      for (int g=0; g<4; ++g)
        acc[g] = __builtin_amdgcn_mfma_f32_16x16x32_bf16(Af[kit], Bf[g][kit], acc[g],0,0,0);

    // single-pass cross-wave reduce, all 4 gates, double-buffered
    const int pb = t & 1;
    #pragma unroll
    for (int g=0; g<4; ++g) part[pb][wave][g][lane] = acc[g];
    __syncthreads();

    float gv[4];
    #pragma unroll
    for (int g=0; g<4; ++g){
      float s = bf2f(xwc[g]);
      #pragma unroll
      for (int w=0; w<4; ++w)
        s += ((const float*)&part[pb][w][g][ln])[rg];
      gv[g] = s;
    }

    float it = sigm(gv[0]), ft = sigm(gv[1]), ch = tanhx(gv[2]), ot = sigm(gv[3]);
    cc = cc*ft + it*ch;
    float hv = ot * tanhx(cc);

    // pack 4 adjacent cells -> one 8B write-through store
    u32 w0 = (u32)(unsigned short)bf16b(hv);
    u32 w1 = __shfl_down(w0, 1);
    u32 w2 = __shfl_down(w0, 2);
    u32 w3 = __shfl_down(w0, 3);
    if (!(tid & 3)){
      u64 hp = (u64)w0 | ((u64)w1<<16) | ((u64)w2<<32) | ((u64)w3<<48);
      __hip_atomic_store((u64*)(hout + (size_t)(b0 + r)*HID + j0 + jj), hp,
                         __ATOMIC_RELAXED, __HIP_MEMORY_SCOPE_AGENT);
    }
    xwc[0]=xwn[0]; xwc[1]=xwn[1]; xwc[2]=xwn[2]; xwc[3]=xwn[3];
    __syncthreads();   // all waves' h stores drained (vmcnt0 at barrier)

    if (t < SQLEN-1 && tid == 0)
      __hip_atomic_store(fgrp + jg, (u32)(t+1), __ATOMIC_RELAXED,
                         __HIP_MEMORY_SCOPE_AGENT);   // plain store, no RMW
  }
}

// ---- phase 3: out[b][c] = h[b]. Wfc[c] + bfc[c], fp32. 256 blocks. ----
__global__ __launch_bounds__(256) void fc_kernel(const short* __restrict__ h,
    const float* __restrict__ wfc, const float* __restrict__ bfc, float* __restrict__ out)
{
  __shared__ float hs[4][1024];
  int tid = threadIdx.x;
  int b0 = (blockIdx.x >> 3)*4;
  int cs = (blockIdx.x & 7)*125;
  for (int i = tid; i < 4096; i += 256){
    int bb = i >> 10, k = i & 1023;
    hs[bb][k] = bf2f(h[(size_t)(b0+bb)*HID + k]);
  }
  __syncthreads();
  for (int c = cs + tid; c < cs + 125; c += 256){
    const float* w = wfc + (size_t)c*HID;
    float a0=0.f,a1=0.f,a2=0.f,a3=0.f;
    for (int k=0; k<1024; k+=4){
      float4 wv = *(const float4*)(w + k);
      a0 += wv.x*hs[0][k] + wv.y*hs[0][k+1] + wv.z*hs[0][k+2] + wv.w*hs[0][k+3];
      a1 += wv.x*hs[1][k] + wv.y*hs[1][k+1] + wv.z*hs[1][k+2] + wv.w*hs[1][k+3];
      a2 += wv.x*hs[2][k] + wv.y*hs[2][k+1] + wv.z*hs[2][k+2] + wv.w*hs[2][k+3];
      a3 += wv.x*hs[3][k] + wv.y*hs[3][k+1] + wv.z*hs[3][k+2] + wv.w*hs[3][k+3];
    }
    float bb = bfc[c];
    out[(size_t)(b0+0)*NCLS + c] = a0 + bb;
    out[(size_t)(b0+1)*NCLS + c] = a1 + bb;
    out[(size_t)(b0+2)*NCLS + c] = a2 + bb;
    out[(size_t)(b0+3)*NCLS + c] = a3 + bb;
  }
}

extern "C" void kernel_launch(void* const* d_in, const int* in_sizes, int n_in,
                              void* d_out, int out_size, void* d_ws, size_t ws_size,
                              hipStream_t stream) {
  const float* x   = (const float*)d_in[0];
  const float* Wxh = (const float*)d_in[1];
  const float* bxh = (const float*)d_in[2];
  const float* Whh = (const float*)d_in[3];
  const float* bhh = (const float*)d_in[4];
  const float* Wfc = (const float*)d_in[5];
  const float* bfc = (const float*)d_in[6];
  float* out = (float*)d_out;

  char* ws = (char*)d_ws;
  // xbf stays LIVE through the mega kernel (gemm A source) -> h_all does
  // NOT alias it; workspace high-water ~422 MB (same map as R6-R8, ran OK).
  short*    xbf   = (short*)(ws + 0);            // 64 MB
  short*    wxhb  = (short*)(ws + 68157440);     // 65 MB
  short*    whhb  = (short*)(ws + 76546048);     // 73 MB
  float*    biasg = (float*)(ws + 84934656);     // 81 MB
  short*    xw    = (short*)(ws + 85983232);     // 82 MB, 256 MB gate-blocked
  short*    h_all = (short*)(ws + 354418688);    // 338 MB, 257 x 256 KB
  u32*      flags = (u32*)(ws + 421789696);      // 512 h-flags
  u32*      gcnt  = (u32*)(ws + 421793792);      // 256 per-s gemm counters

  hipMemsetAsync(flags, 0, 8192, stream);        // covers flags + gcnt

  cast_x_kernel<<<32768, 256, 0, stream>>>(x, xbf);
  cast_w_kernel<<<4096, 256, 0, stream>>>(Wxh, wxhb);
  cast_w_kernel<<<4096, 256, 0, stream>>>(Whh, whhb);
  bias_kernel  <<<16,   256, 0, stream>>>(bxh, bhh, biasg);
  hipMemsetAsync(h_all, 0, 262144, stream);      // h_all[0] = 0
  mega_kernel<<<1024, 256, 0, stream>>>(xbf, wxhb, biasg, whhb,
                                        xw, h_all, flags, gcnt);
  fc_kernel    <<<256,  256, 0, stream>>>(h_all + (size_t)SQLEN*131072, Wfc, bfc, out);
}

// Round 13
// 1592.561 us; speedup vs baseline: 2.0215x; 2.0215x over previous
//
#include <hip/hip_runtime.h>
#include <hip/hip_bf16.h>

typedef __attribute__((ext_vector_type(8))) short short8;
typedef __attribute__((ext_vector_type(4))) float f32x4;
typedef unsigned long long u64;
typedef unsigned int u32;

#define SQLEN 256
#define BATCH 128
#define HID   1024
#define G4    4096
#define NCLS  1000

static __device__ __forceinline__ float sigm(float x){ return 1.0f/(1.0f+__expf(-x)); }
static __device__ __forceinline__ float tanhx(float x){ return 2.0f/(1.0f+__expf(-2.0f*x)) - 1.0f; }
static __device__ __forceinline__ short bf16b(float x){
  __hip_bfloat16 h = __float2bfloat16(x);
  return __builtin_bit_cast(short, h);
}
static __device__ __forceinline__ float bf2f(short s){
  return __bfloat162float(__builtin_bit_cast(__hip_bfloat16, s));
}

// ---- prep: cast x [B][S][I] fp32 -> xbf [(s*128+b)][I] bf16 (permuted) ----
__global__ void cast_x_kernel(const float* __restrict__ x, short* __restrict__ xbf){
  int r = blockIdx.x;            // r = s*128 + b
  int s = r >> 7, b = r & 127;
  const float* src = x + ((size_t)b*SQLEN + s)*HID;
  short* dst = xbf + (size_t)r*HID;
  int k = threadIdx.x*4;
  float4 v = *(const float4*)(src + k);
  short4 o; o.x=bf16b(v.x); o.y=bf16b(v.y); o.z=bf16b(v.z); o.w=bf16b(v.w);
  *(short4*)(dst + k) = o;
}

// ---- fused prep: cast Wxh (blocks 0..4095), Whh (4096..8191), bias (8192..8207)
// (merges 3 kernel launches into 1 -- pure launch-overhead removal)
__global__ void cast_prep_kernel(const float* __restrict__ Wxh,
                                 const float* __restrict__ Whh,
                                 const float* __restrict__ bxh,
                                 const float* __restrict__ bhh,
                                 short* __restrict__ wxhb,
                                 short* __restrict__ whhb,
                                 float* __restrict__ biasg){
  int b = blockIdx.x;
  if (b < 8192){
    const float* src = (b < 4096) ? Wxh : Whh;
    short*       dst = (b < 4096) ? wxhb : whhb;
    int bb = b & 4095;
    int i = (bb*256 + threadIdx.x)*4;
    float4 v = *(const float4*)(src + i);
    short4 o; o.x=bf16b(v.x); o.y=bf16b(v.y); o.z=bf16b(v.z); o.w=bf16b(v.w);
    *(short4*)(dst + i) = o;
  } else {
    int i = (b - 8192)*256 + threadIdx.x;
    biasg[i] = bxh[i] + bhh[i];
  }
}

// ---- phase 1: xw GEMM (M=32768,N=4096,K=1024). global_load_lds staging.
// Output gate-blocked: xw[((s*64 + jg)*128 + b)*64 + g*16 + jj]
// R9 structure (proven, ~470us) with TWO deltas:
//  * XCD-chunked bijective swizzle (T1, proven R9: A-panels XCD-L2-resident)
//  * launch_bounds(256,4): VGPR cap 170->128 (liveness ~120 fits), LDS
//    16KB -> 4 blocks/CU instead of 3. More resident waves = more implicit
//    overlap of the per-kk vmcnt drains (m114 mechanism) -> expected +10%.
__global__ __launch_bounds__(256,4) void gemm_xw_kernel(
    const short* __restrict__ A, const short* __restrict__ B,
    const float* __restrict__ bias, short* __restrict__ C)
{
  __shared__ __align__(16) short As[4096];   // [128][32]
  __shared__ __align__(16) short Bs[4096];
  const int tid = threadIdx.x;
  const int swz = (((int)blockIdx.x & 7) << 10) + ((int)blockIdx.x >> 3);
  const int bm = swz >> 5;            // 0..255  (= s index)
  const int bn = swz & 31;            // 0..31
  const size_t r0 = (size_t)bm*128, n0 = (size_t)bn*128;
  const int lane = tid & 63, wave = tid >> 6;
  const int wm = (wave>>1)*64, wn = (wave&1)*64;
  const int l15 = lane & 15, quad = lane >> 4;

  f32x4 acc[4][4];
  #pragma unroll
  for (int m=0;m<4;++m)
    #pragma unroll
    for (int n=0;n<4;++n) acc[m][n] = (f32x4)0.0f;

  const int c0 = wave*64 + lane;      // staging slot, rep 0
  const int c1 = c0 + 256;            // rep 1

  for (int kk = 0; kk < 32; ++kk){
    const int k0 = kk*32;
    __syncthreads();   // previous iter's LDS reads done
    // async DMA global -> LDS, 16B per lane, lane-contiguous dest
    __builtin_amdgcn_global_load_lds(
        (const void*)(A + (r0 + (c0>>2))*HID + k0 + (c0&3)*8),
        (void*)((char*)As + wave*1024), 16, 0, 0);
    __builtin_amdgcn_global_load_lds(
        (const void*)(A + (r0 + (c1>>2))*HID + k0 + (c1&3)*8),
        (void*)((char*)As + 4096 + wave*1024), 16, 0, 0);
    __builtin_amdgcn_global_load_lds(
        (const void*)(B + (n0 + (c0>>2))*HID + k0 + (c0&3)*8),
        (void*)((char*)Bs + wave*1024), 16, 0, 0);
    __builtin_amdgcn_global_load_lds(
        (const void*)(B + (n0 + (c1>>2))*HID + k0 + (c1&3)*8),
        (void*)((char*)Bs + 4096 + wave*1024), 16, 0, 0);
    __syncthreads();   // DMA landed (barrier drains vmcnt)
    short8 af[4], bf[4];
    #pragma unroll
    for (int m=0;m<4;++m) af[m] = *(const short8*)(As + (wm + m*16 + l15)*32 + quad*8);
    #pragma unroll
    for (int n=0;n<4;++n) bf[n] = *(const short8*)(Bs + (wn + n*16 + l15)*32 + quad*8);
    #pragma unroll
    for (int m=0;m<4;++m)
      #pragma unroll
      for (int n=0;n<4;++n)
        acc[m][n] = __builtin_amdgcn_mfma_f32_16x16x32_bf16(af[m], bf[n], acc[m][n], 0,0,0);
  }
  // epilogue: pack 4 adjacent bf16 -> 8B stores
  #pragma unroll
  for (int n=0;n<4;++n){
    int s = (int)n0 + wn + n*16;          // start col, multiple of 16
    float bs = bias[s + l15];
    int g = s >> 10, jgi = (s & 1023) >> 4;
    #pragma unroll
    for (int m=0;m<4;++m){
      #pragma unroll
      for (int rg=0; rg<4; ++rg){
        u32 w0 = (u32)(unsigned short)bf16b(acc[m][n][rg] + bs);
        u32 w1 = __shfl_down(w0, 1);
        u32 w2 = __shfl_down(w0, 2);
        u32 w3 = __shfl_down(w0, 3);
        if ((l15 & 3) == 0){
          u64 pk = (u64)w0 | ((u64)w1<<16) | ((u64)w2<<32) | ((u64)w3<<48);
          int rowin = wm + m*16 + quad*4 + rg;    // batch b 0..127
          *(u64*)(C + (((size_t)bm*64 + jgi)*128 + rowin)*64 + g*16 + l15) = pk;
        }
      }
    }
  }
}

// ---- phase 2: persistent LSTM recurrence -- BYTE-EXACT R1 (962us, banked;
// 0/5 on modifications, 0/4 on fusion attempts). ----
__global__ __launch_bounds__(256,2) void lstm_kernel(
    const short* __restrict__ whh, const short* __restrict__ xw,
    short* __restrict__ h_all, u32* __restrict__ flags)
{
  __shared__ f32x4 part[2][4][4][64];   // [buf][wave][gate][lane] = 32 KB

  const int tid  = threadIdx.x;
  const int lane = tid & 63;
  const int wave = tid >> 6;            // K-slice 0..3 (256 each)
  const int l15  = lane & 15;
  const int quad = lane >> 4;
  const int bg = blockIdx.x & 7;        // batch group
  const int jg = blockIdx.x >> 3;       // 0..63
  const int b0 = bg*16;
  const int j0 = jg*16;
  const int ks0 = wave*256;

  __builtin_amdgcn_fence(__ATOMIC_ACQUIRE, "agent");  // once: clear stale L2

  // Whh slice, MFMA B-fragment layout (no pinning -- rounds 2/3)
  short8 Bf[4][8];
  #pragma unroll
  for (int g=0; g<4; ++g)
    #pragma unroll
    for (int kit=0; kit<8; ++kit)
      Bf[g][kit] = *(const short8*)(whh + (size_t)(g*1024 + j0 + l15)*HID
                                    + ks0 + kit*32 + quad*8);

  u32* fgrp = flags + bg*64;            // one flag per producer block

  // elementwise cell mapping: cell = tid (r 0..15 x jj 0..15)
  const int r  = tid >> 4;
  const int jj = tid & 15;
  const int ln = (r>>2)*16 + jj;        // frag lane of cell
  const int rg = r & 3;                 // frag reg of cell
  float cc = 0.0f;                      // cell state in register

  // prefetch xw for t=0
  short xwc[4];
  {
    const short* xb = xw + (((size_t)0*64 + jg)*128 + b0 + r)*64 + jj;
    #pragma unroll
    for (int g=0; g<4; ++g) xwc[g] = xb[g*16];
  }

  for (int t = 0; t < SQLEN; ++t){
    const short* hin  = h_all + (size_t)t*131072;
    short*       hout = h_all + (size_t)(t+1)*131072;

    // prefetch next step's xw early (independent of h)
    short xwn[4];
    if (t < SQLEN-1){
      const short* xb = xw + (((size_t)(t+1)*64 + jg)*128 + b0 + r)*64 + jj;
      #pragma unroll
      for (int g=0; g<4; ++g) xwn[g] = xb[g*16];
    }

    // per-wave spin: only the 16 producer blocks of THIS wave's K-slice.
    if (t){
      u32* fp = fgrp + wave*16 + l15;
      while (__hip_atomic_load(fp, __ATOMIC_RELAXED,
                               __HIP_MEMORY_SCOPE_AGENT) < (u32)t)
        __builtin_amdgcn_s_sleep(1);
      asm volatile("" ::: "memory");    // no hoist of h loads above the spin
    }

    // h fragments: plain cached coalesced 16B loads (fresh addresses)
    short8 Af[8];
    #pragma unroll
    for (int kit=0; kit<8; ++kit)
      Af[kit] = *(const short8*)(hin + (size_t)(b0 + l15)*HID
                                 + ks0 + kit*32 + quad*8);

    f32x4 acc[4];
    #pragma unroll
    for (int g=0; g<4; ++g) acc[g] = (f32x4)0.0f;
    #pragma unroll
    for (int kit=0; kit<8; ++kit)
      #pragma unroll
      for (int g=0; g<4; ++g)
        acc[g] = __builtin_amdgcn_mfma_f32_16x16x32_bf16(Af[kit], Bf[g][kit], acc[g],0,0,0);

    // single-pass cross-wave reduce, all 4 gates, double-buffered
    const int pb = t & 1;
    #pragma unroll
    for (int g=0; g<4; ++g) part[pb][wave][g][lane] = acc[g];
    __syncthreads();

    float gv[4];
    #pragma unroll
    for (int g=0; g<4; ++g){
      float s = bf2f(xwc[g]);
      #pragma unroll
      for (int w=0; w<4; ++w)
        s += ((const float*)&part[pb][w][g][ln])[rg];
      gv[g] = s;
    }

    float it = sigm(gv[0]), ft = sigm(gv[1]), ch = tanhx(gv[2]), ot = sigm(gv[3]);
    cc = cc*ft + it*ch;
    float hv = ot * tanhx(cc);

    // pack 4 adjacent cells -> one 8B write-through store
    u32 w0 = (u32)(unsigned short)bf16b(hv);
    u32 w1 = __shfl_down(w0, 1);
    u32 w2 = __shfl_down(w0, 2);
    u32 w3 = __shfl_down(w0, 3);
    if (!(tid & 3)){
      u64 hp = (u64)w0 | ((u64)w1<<16) | ((u64)w2<<32) | ((u64)w3<<48);
      __hip_atomic_store((u64*)(hout + (size_t)(b0 + r)*HID + j0 + jj), hp,
                         __ATOMIC_RELAXED, __HIP_MEMORY_SCOPE_AGENT);
    }
    xwc[0]=xwn[0]; xwc[1]=xwn[1]; xwc[2]=xwn[2]; xwc[3]=xwn[3];
    __syncthreads();   // all waves' h stores drained (vmcnt0 at barrier)

    if (t < SQLEN-1 && tid == 0)
      __hip_atomic_store(fgrp + jg, (u32)(t+1), __ATOMIC_RELAXED,
                         __HIP_MEMORY_SCOPE_AGENT);   // plain store, no RMW
  }
}

// ---- phase 3: out[b][c] = h[b]. Wfc[c] + bfc[c], fp32. 256 blocks:
// 32 b-groups x 8 class-slices of 125 (proven). ----
__global__ __launch_bounds__(256) void fc_kernel(const short* __restrict__ h,
    const float* __restrict__ wfc, const float* __restrict__ bfc, float* __restrict__ out)
{
  __shared__ float hs[4][1024];
  int tid = threadIdx.x;
  int b0 = (blockIdx.x >> 3)*4;
  int cs = (blockIdx.x & 7)*125;
  for (int i = tid; i < 4096; i += 256){
    int bb = i >> 10, k = i & 1023;
    hs[bb][k] = bf2f(h[(size_t)(b0+bb)*HID + k]);
  }
  __syncthreads();
  for (int c = cs + tid; c < cs + 125; c += 256){
    const float* w = wfc + (size_t)c*HID;
    float a0=0.f,a1=0.f,a2=0.f,a3=0.f;
    for (int k=0; k<1024; k+=4){
      float4 wv = *(const float4*)(w + k);
      a0 += wv.x*hs[0][k] + wv.y*hs[0][k+1] + wv.z*hs[0][k+2] + wv.w*hs[0][k+3];
      a1 += wv.x*hs[1][k] + wv.y*hs[1][k+1] + wv.z*hs[1][k+2] + wv.w*hs[1][k+3];
      a2 += wv.x*hs[2][k] + wv.y*hs[2][k+1] + wv.z*hs[2][k+2] + wv.w*hs[2][k+3];
      a3 += wv.x*hs[3][k] + wv.y*hs[3][k+1] + wv.z*hs[3][k+2] + wv.w*hs[3][k+3];
    }
    float bb = bfc[c];
    out[(size_t)(b0+0)*NCLS + c] = a0 + bb;
    out[(size_t)(b0+1)*NCLS + c] = a1 + bb;
    out[(size_t)(b0+2)*NCLS + c] = a2 + bb;
    out[(size_t)(b0+3)*NCLS + c] = a3 + bb;
  }
}

extern "C" void kernel_launch(void* const* d_in, const int* in_sizes, int n_in,
                              void* d_out, int out_size, void* d_ws, size_t ws_size,
                              hipStream_t stream) {
  const float* x   = (const float*)d_in[0];
  const float* Wxh = (const float*)d_in[1];
  const float* bxh = (const float*)d_in[2];
  const float* Whh = (const float*)d_in[3];
  const float* bhh = (const float*)d_in[4];
  const float* Wfc = (const float*)d_in[5];
  const float* bfc = (const float*)d_in[6];
  float* out = (float*)d_out;

  char* ws = (char*)d_ws;
  // h_all (257 x 256KB = 64.25MB) ALIASES xbf (64MB): xbf dead after gemm.
  short*    h_all = (short*)(ws + 0);
  short*    xbf   = (short*)(ws + 0);
  short*    wxhb  = (short*)(ws + 68157440);     // 65 MB
  short*    whhb  = (short*)(ws + 76546048);     // 73 MB
  float*    biasg = (float*)(ws + 84934656);     // 81 MB
  short*    xw    = (short*)(ws + 85983232);     // 82 MB, 256 MB gate-blocked
  u32*      flags = (u32*)(ws + 354418688);      // 512 producer flags

  hipMemsetAsync(flags, 0, 4096, stream);

  cast_x_kernel<<<32768, 256, 0, stream>>>(x, xbf);
  cast_prep_kernel<<<8208, 256, 0, stream>>>(Wxh, Whh, bxh, bhh, wxhb, whhb, biasg);
  gemm_xw_kernel<<<8192, 256, 0, stream>>>(xbf, wxhb, biasg, xw);
  // xbf now dead; zero h_all[0] (t=0 input state)
  hipMemsetAsync(ws, 0, 262144, stream);
  lstm_kernel  <<<512,  256, 0, stream>>>(whhb, xw, h_all, flags);
  fc_kernel    <<<256,  256, 0, stream>>>(h_all + (size_t)SQLEN*131072, Wfc, bfc, out);
}

// Round 14
// 1580.157 us; speedup vs baseline: 2.0374x; 1.0078x over previous
//
#include <hip/hip_runtime.h>
#include <hip/hip_bf16.h>

typedef __attribute__((ext_vector_type(8))) short short8;
typedef __attribute__((ext_vector_type(4))) float f32x4;
typedef unsigned long long u64;
typedef unsigned int u32;

#define SQLEN 256
#define BATCH 128
#define HID   1024
#define G4    4096
#define NCLS  1000

static __device__ __forceinline__ float sigm(float x){ return 1.0f/(1.0f+__expf(-x)); }
static __device__ __forceinline__ float tanhx(float x){ return 2.0f/(1.0f+__expf(-2.0f*x)) - 1.0f; }
static __device__ __forceinline__ short bf16b(float x){
  __hip_bfloat16 h = __float2bfloat16(x);
  return __builtin_bit_cast(short, h);
}
static __device__ __forceinline__ float bf2f(short s){
  return __bfloat162float(__builtin_bit_cast(__hip_bfloat16, s));
}

// ---- prep: cast x [B][S][I] fp32 -> xbf [(s*128+b)][I] bf16 (permuted) ----
// 4096 blocks x 8 rows each (was 32768 x 1: dispatch-rate bound at ~1KB of
// work per block). Per-row reads stay fully coalesced (float4/lane); the 8
// rows give 8 independent load streams per block.
__global__ void cast_x_kernel(const float* __restrict__ x, short* __restrict__ xbf){
  const int base = blockIdx.x * 8;
  const int k = threadIdx.x * 4;
  #pragma unroll
  for (int i = 0; i < 8; ++i){
    int r = base + i;                // r = s*128 + b
    int s = r >> 7, b = r & 127;
    const float* src = x + ((size_t)b*SQLEN + s)*HID;
    float4 v = *(const float4*)(src + k);
    short4 o; o.x=bf16b(v.x); o.y=bf16b(v.y); o.z=bf16b(v.z); o.w=bf16b(v.w);
    *(short4*)(xbf + (size_t)r*HID + k) = o;
  }
}

// ---- fused prep: cast Wxh (blocks 0..4095), Whh (4096..8191), bias (8192..8207)
__global__ void cast_prep_kernel(const float* __restrict__ Wxh,
                                 const float* __restrict__ Whh,
                                 const float* __restrict__ bxh,
                                 const float* __restrict__ bhh,
                                 short* __restrict__ wxhb,
                                 short* __restrict__ whhb,
                                 float* __restrict__ biasg){
  int b = blockIdx.x;
  if (b < 8192){
    const float* src = (b < 4096) ? Wxh : Whh;
    short*       dst = (b < 4096) ? wxhb : whhb;
    int bb = b & 4095;
    int i = (bb*256 + threadIdx.x)*4;
    float4 v = *(const float4*)(src + i);
    short4 o; o.x=bf16b(v.x); o.y=bf16b(v.y); o.z=bf16b(v.z); o.w=bf16b(v.w);
    *(short4*)(dst + i) = o;
  } else {
    int i = (b - 8192)*256 + threadIdx.x;
    biasg[i] = bxh[i] + bhh[i];
  }
}

// ---- phase 1: xw GEMM (M=32768,N=4096,K=1024). global_load_lds staging.
// Output gate-blocked: xw[((s*64 + jg)*128 + b)*64 + g*16 + jj]
// Swizzle v2 -- B-resident partition. R9's swizzle (bn fastest per XCD)
// made A-panels L2-local but swept all of B (8MB) through each 4MB XCD L2
// EVERY bm-round: ~2GB of L3->L2 B traffic. v2 inverts the partition:
//   c = bid&7 (XCD), bn = c*4 + ((bid>>3)&3), bm = bid>>5.
// Each XCD owns a FIXED 4-column B-chunk (1MB -> permanently L2-resident,
// zero re-reads) and walks bm with 4 consecutive same-XCD blocks sharing
// each A-panel (A = 64MB/XCD streamed once from L3). Per-XCD traffic
// 264MB -> 65MB (4x). Bijective: bid = bm*32 + (bn&3)*8 + (bn>>2)... i.e.
// (c, rr) <-> (bm, bn) one-to-one over 8192. Everything else = R13.
__global__ __launch_bounds__(256,4) void gemm_xw_kernel(
    const short* __restrict__ A, const short* __restrict__ B,
    const float* __restrict__ bias, short* __restrict__ C)
{
  __shared__ __align__(16) short As[4096];   // [128][32]
  __shared__ __align__(16) short Bs[4096];
  const int tid = threadIdx.x;
  const int bid = (int)blockIdx.x;
  const int c   = bid & 7;            // XCD (round-robin dispatch)
  const int rr  = bid >> 3;           // 0..1023 within XCD
  const int bn  = c*4 + (rr & 3);     // fixed 4-column B set per XCD
  const int bm  = rr >> 2;            // 0..255 (= s index)
  const size_t r0 = (size_t)bm*128, n0 = (size_t)bn*128;
  const int lane = tid & 63, wave = tid >> 6;
  const int wm = (wave>>1)*64, wn = (wave&1)*64;
  const int l15 = lane & 15, quad = lane >> 4;

  f32x4 acc[4][4];
  #pragma unroll
  for (int m=0;m<4;++m)
    #pragma unroll
    for (int n=0;n<4;++n) acc[m][n] = (f32x4)0.0f;

  const int c0 = wave*64 + lane;      // staging slot, rep 0
  const int c1 = c0 + 256;            // rep 1

  for (int kk = 0; kk < 32; ++kk){
    const int k0 = kk*32;
    __syncthreads();   // previous iter's LDS reads done
    // async DMA global -> LDS, 16B per lane, lane-contiguous dest
    __builtin_amdgcn_global_load_lds(
        (const void*)(A + (r0 + (c0>>2))*HID + k0 + (c0&3)*8),
        (void*)((char*)As + wave*1024), 16, 0, 0);
    __builtin_amdgcn_global_load_lds(
        (const void*)(A + (r0 + (c1>>2))*HID + k0 + (c1&3)*8),
        (void*)((char*)As + 4096 + wave*1024), 16, 0, 0);
    __builtin_amdgcn_global_load_lds(
        (const void*)(B + (n0 + (c0>>2))*HID + k0 + (c0&3)*8),
        (void*)((char*)Bs + wave*1024), 16, 0, 0);
    __builtin_amdgcn_global_load_lds(
        (const void*)(B + (n0 + (c1>>2))*HID + k0 + (c1&3)*8),
        (void*)((char*)Bs + 4096 + wave*1024), 16, 0, 0);
    __syncthreads();   // DMA landed (barrier drains vmcnt)
    short8 af[4], bf[4];
    #pragma unroll
    for (int m=0;m<4;++m) af[m] = *(const short8*)(As + (wm + m*16 + l15)*32 + quad*8);
    #pragma unroll
    for (int n=0;n<4;++n) bf[n] = *(const short8*)(Bs + (wn + n*16 + l15)*32 + quad*8);
    #pragma unroll
    for (int m=0;m<4;++m)
      #pragma unroll
      for (int n=0;n<4;++n)
        acc[m][n] = __builtin_amdgcn_mfma_f32_16x16x32_bf16(af[m], bf[n], acc[m][n], 0,0,0);
  }
  // epilogue: pack 4 adjacent bf16 -> 8B stores
  #pragma unroll
  for (int n=0;n<4;++n){
    int s = (int)n0 + wn + n*16;          // start col, multiple of 16
    float bs = bias[s + l15];
    int g = s >> 10, jgi = (s & 1023) >> 4;
    #pragma unroll
    for (int m=0;m<4;++m){
      #pragma unroll
      for (int rg=0; rg<4; ++rg){
        u32 w0 = (u32)(unsigned short)bf16b(acc[m][n][rg] + bs);
        u32 w1 = __shfl_down(w0, 1);
        u32 w2 = __shfl_down(w0, 2);
        u32 w3 = __shfl_down(w0, 3);
        if ((l15 & 3) == 0){
          u64 pk = (u64)w0 | ((u64)w1<<16) | ((u64)w2<<32) | ((u64)w3<<48);
          int rowin = wm + m*16 + quad*4 + rg;    // batch b 0..127
          *(u64*)(C + (((size_t)bm*64 + jgi)*128 + rowin)*64 + g*16 + l15) = pk;
        }
      }
    }
  }
}

// ---- phase 2: persistent LSTM recurrence -- BYTE-EXACT R1 (962us, banked;
// 0/5 on modifications, 0/4 on fusion attempts). ----
__global__ __launch_bounds__(256,2) void lstm_kernel(
    const short* __restrict__ whh, const short* __restrict__ xw,
    short* __restrict__ h_all, u32* __restrict__ flags)
{
  __shared__ f32x4 part[2][4][4][64];   // [buf][wave][gate][lane] = 32 KB

  const int tid  = threadIdx.x;
  const int lane = tid & 63;
  const int wave = tid >> 6;            // K-slice 0..3 (256 each)
  const int l15  = lane & 15;
  const int quad = lane >> 4;
  const int bg = blockIdx.x & 7;        // batch group
  const int jg = blockIdx.x >> 3;       // 0..63
  const int b0 = bg*16;
  const int j0 = jg*16;
  const int ks0 = wave*256;

  __builtin_amdgcn_fence(__ATOMIC_ACQUIRE, "agent");  // once: clear stale L2

  // Whh slice, MFMA B-fragment layout (no pinning -- rounds 2/3)
  short8 Bf[4][8];
  #pragma unroll
  for (int g=0; g<4; ++g)
    #pragma unroll
    for (int kit=0; kit<8; ++kit)
      Bf[g][kit] = *(const short8*)(whh + (size_t)(g*1024 + j0 + l15)*HID
                                    + ks0 + kit*32 + quad*8);

  u32* fgrp = flags + bg*64;            // one flag per producer block

  // elementwise cell mapping: cell = tid (r 0..15 x jj 0..15)
  const int r  = tid >> 4;
  const int jj = tid & 15;
  const int ln = (r>>2)*16 + jj;        // frag lane of cell
  const int rg = r & 3;                 // frag reg of cell
  float cc = 0.0f;                      // cell state in register

  // prefetch xw for t=0
  short xwc[4];
  {
    const short* xb = xw + (((size_t)0*64 + jg)*128 + b0 + r)*64 + jj;
    #pragma unroll
    for (int g=0; g<4; ++g) xwc[g] = xb[g*16];
  }

  for (int t = 0; t < SQLEN; ++t){
    const short* hin  = h_all + (size_t)t*131072;
    short*       hout = h_all + (size_t)(t+1)*131072;

    // prefetch next step's xw early (independent of h)
    short xwn[4];
    if (t < SQLEN-1){
      const short* xb = xw + (((size_t)(t+1)*64 + jg)*128 + b0 + r)*64 + jj;
      #pragma unroll
      for (int g=0; g<4; ++g) xwn[g] = xb[g*16];
    }

    // per-wave spin: only the 16 producer blocks of THIS wave's K-slice.
    if (t){
      u32* fp = fgrp + wave*16 + l15;
      while (__hip_atomic_load(fp, __ATOMIC_RELAXED,
                               __HIP_MEMORY_SCOPE_AGENT) < (u32)t)
        __builtin_amdgcn_s_sleep(1);
      asm volatile("" ::: "memory");    // no hoist of h loads above the spin
    }

    // h fragments: plain cached coalesced 16B loads (fresh addresses)
    short8 Af[8];
    #pragma unroll
    for (int kit=0; kit<8; ++kit)
      Af[kit] = *(const short8*)(hin + (size_t)(b0 + l15)*HID
                                 + ks0 + kit*32 + quad*8);

    f32x4 acc[4];
    #pragma unroll
    for (int g=0; g<4; ++g) acc[g] = (f32x4)0.0f;
    #pragma unroll
    for (int kit=0; kit<8; ++kit)
      #pragma unroll
      for (int g=0; g<4; ++g)
        acc[g] = __builtin_amdgcn_mfma_f32_16x16x32_bf16(Af[kit], Bf[g][kit], acc[g],0,0,0);

    // single-pass cross-wave reduce, all 4 gates, double-buffered
    const int pb = t & 1;
    #pragma unroll
    for (int g=0; g<4; ++g) part[pb][wave][g][lane] = acc[g];
    __syncthreads();

    float gv[4];
    #pragma unroll
    for (int g=0; g<4; ++g){
      float s = bf2f(xwc[g]);
      #pragma unroll
      for (int w=0; w<4; ++w)
        s += ((const float*)&part[pb][w][g][ln])[rg];
      gv[g] = s;
    }

    float it = sigm(gv[0]), ft = sigm(gv[1]), ch = tanhx(gv[2]), ot = sigm(gv[3]);
    cc = cc*ft + it*ch;
    float hv = ot * tanhx(cc);

    // pack 4 adjacent cells -> one 8B write-through store
    u32 w0 = (u32)(unsigned short)bf16b(hv);
    u32 w1 = __shfl_down(w0, 1);
    u32 w2 = __shfl_down(w0, 2);
    u32 w3 = __shfl_down(w0, 3);
    if (!(tid & 3)){
      u64 hp = (u64)w0 | ((u64)w1<<16) | ((u64)w2<<32) | ((u64)w3<<48);
      __hip_atomic_store((u64*)(hout + (size_t)(b0 + r)*HID + j0 + jj), hp,
                         __ATOMIC_RELAXED, __HIP_MEMORY_SCOPE_AGENT);
    }
    xwc[0]=xwn[0]; xwc[1]=xwn[1]; xwc[2]=xwn[2]; xwc[3]=xwn[3];
    __syncthreads();   // all waves' h stores drained (vmcnt0 at barrier)

    if (t < SQLEN-1 && tid == 0)
      __hip_atomic_store(fgrp + jg, (u32)(t+1), __ATOMIC_RELAXED,
                         __HIP_MEMORY_SCOPE_AGENT);   // plain store, no RMW
  }
}

// ---- phase 3: out[b][c] = h[b]. Wfc[c] + bfc[c], fp32. 256 blocks:
// 32 b-groups x 8 class-slices of 125 (proven). ----
__global__ __launch_bounds__(256) void fc_kernel(const short* __restrict__ h,
    const float* __restrict__ wfc, const float* __restrict__ bfc, float* __restrict__ out)
{
  __shared__ float hs[4][1024];
  int tid = threadIdx.x;
  int b0 = (blockIdx.x >> 3)*4;
  int cs = (blockIdx.x & 7)*125;
  for (int i = tid; i < 4096; i += 256){
    int bb = i >> 10, k = i & 1023;
    hs[bb][k] = bf2f(h[(size_t)(b0+bb)*HID + k]);
  }
  __syncthreads();
  for (int c = cs + tid; c < cs + 125; c += 256){
    const float* w = wfc + (size_t)c*HID;
    float a0=0.f,a1=0.f,a2=0.f,a3=0.f;
    for (int k=0; k<1024; k+=4){
      float4 wv = *(const float4*)(w + k);
      a0 += wv.x*hs[0][k] + wv.y*hs[0][k+1] + wv.z*hs[0][k+2] + wv.w*hs[0][k+3];
      a1 += wv.x*hs[1][k] + wv.y*hs[1][k+1] + wv.z*hs[1][k+2] + wv.w*hs[1][k+3];
      a2 += wv.x*hs[2][k] + wv.y*hs[2][k+1] + wv.z*hs[2][k+2] + wv.w*hs[2][k+3];
      a3 += wv.x*hs[3][k] + wv.y*hs[3][k+1] + wv.z*hs[3][k+2] + wv.w*hs[3][k+3];
    }
    float bb = bfc[c];
    out[(size_t)(b0+0)*NCLS + c] = a0 + bb;
    out[(size_t)(b0+1)*NCLS + c] = a1 + bb;
    out[(size_t)(b0+2)*NCLS + c] = a2 + bb;
    out[(size_t)(b0+3)*NCLS + c] = a3 + bb;
  }
}

extern "C" void kernel_launch(void* const* d_in, const int* in_sizes, int n_in,
                              void* d_out, int out_size, void* d_ws, size_t ws_size,
                              hipStream_t stream) {
  const float* x   = (const float*)d_in[0];
  const float* Wxh = (const float*)d_in[1];
  const float* bxh = (const float*)d_in[2];
  const float* Whh = (const float*)d_in[3];
  const float* bhh = (const float*)d_in[4];
  const float* Wfc = (const float*)d_in[5];
  const float* bfc = (const float*)d_in[6];
  float* out = (float*)d_out;

  char* ws = (char*)d_ws;
  // h_all (257 x 256KB = 64.25MB) ALIASES xbf (64MB): xbf dead after gemm.
  short*    h_all = (short*)(ws + 0);
  short*    xbf   = (short*)(ws + 0);
  short*    wxhb  = (short*)(ws + 68157440);     // 65 MB
  short*    whhb  = (short*)(ws + 76546048);     // 73 MB
  float*    biasg = (float*)(ws + 84934656);     // 81 MB
  short*    xw    = (short*)(ws + 85983232);     // 82 MB, 256 MB gate-blocked
  u32*      flags = (u32*)(ws + 354418688);      // 512 producer flags

  hipMemsetAsync(flags, 0, 4096, stream);

  cast_x_kernel<<<4096, 256, 0, stream>>>(x, xbf);
  cast_prep_kernel<<<8208, 256, 0, stream>>>(Wxh, Whh, bxh, bhh, wxhb, whhb, biasg);
  gemm_xw_kernel<<<8192, 256, 0, stream>>>(xbf, wxhb, biasg, xw);
  // xbf now dead; zero h_all[0] (t=0 input state)
  hipMemsetAsync(ws, 0, 262144, stream);
  lstm_kernel  <<<512,  256, 0, stream>>>(whhb, xw, h_all, flags);
  fc_kernel    <<<256,  256, 0, stream>>>(h_all + (size_t)SQLEN*131072, Wfc, bfc, out);
}

// Round 15
// 1568.752 us; speedup vs baseline: 2.0522x; 1.0073x over previous
//
#include <hip/hip_runtime.h>
#include <hip/hip_bf16.h>

typedef __attribute__((ext_vector_type(8))) short short8;
typedef __attribute__((ext_vector_type(4))) float f32x4;
typedef unsigned long long u64;
typedef unsigned int u32;

#define SQLEN 256
#define BATCH 128
#define HID   1024
#define G4    4096
#define NCLS  1000

static __device__ __forceinline__ float sigm(float x){ return 1.0f/(1.0f+__expf(-x)); }
static __device__ __forceinline__ float tanhx(float x){ return 2.0f/(1.0f+__expf(-2.0f*x)) - 1.0f; }
static __device__ __forceinline__ short bf16b(float x){
  __hip_bfloat16 h = __float2bfloat16(x);
  return __builtin_bit_cast(short, h);
}
static __device__ __forceinline__ float bf2f(short s){
  return __bfloat162float(__builtin_bit_cast(__hip_bfloat16, s));
}

// ---- prep: cast x [B][S][I] fp32 -> xbf [(s*128+b)][I] bf16 (permuted) ----
// 4096 blocks x 8 rows each (R14: dispatch-overhead fix, proven).
__global__ void cast_x_kernel(const float* __restrict__ x, short* __restrict__ xbf){
  const int base = blockIdx.x * 8;
  const int k = threadIdx.x * 4;
  #pragma unroll
  for (int i = 0; i < 8; ++i){
    int r = base + i;                // r = s*128 + b
    int s = r >> 7, b = r & 127;
    const float* src = x + ((size_t)b*SQLEN + s)*HID;
    float4 v = *(const float4*)(src + k);
    short4 o; o.x=bf16b(v.x); o.y=bf16b(v.y); o.z=bf16b(v.z); o.w=bf16b(v.w);
    *(short4*)(xbf + (size_t)r*HID + k) = o;
  }
}

// ---- fused prep: cast Wxh (blocks 0..4095), Whh (4096..8191), bias (8192..8207)
__global__ void cast_prep_kernel(const float* __restrict__ Wxh,
                                 const float* __restrict__ Whh,
                                 const float* __restrict__ bxh,
                                 const float* __restrict__ bhh,
                                 short* __restrict__ wxhb,
                                 short* __restrict__ whhb,
                                 float* __restrict__ biasg){
  int b = blockIdx.x;
  if (b < 8192){
    const float* src = (b < 4096) ? Wxh : Whh;
    short*       dst = (b < 4096) ? wxhb : whhb;
    int bb = b & 4095;
    int i = (bb*256 + threadIdx.x)*4;
    float4 v = *(const float4*)(src + i);
    short4 o; o.x=bf16b(v.x); o.y=bf16b(v.y); o.z=bf16b(v.z); o.w=bf16b(v.w);
    *(short4*)(dst + i) = o;
  } else {
    int i = (b - 8192)*256 + threadIdx.x;
    biasg[i] = bxh[i] + bhh[i];
  }
}

// ---- phase 1: xw GEMM (M=32768,N=4096,K=1024). global_load_lds staging.
// R14 structure (B-resident XCD partition, launch_bounds(256,4)) + ONE delta:
// the 256MB C-write stream now uses NON-TEMPORAL stores. Normal stores
// write-allocate in L2, continuously evicting the A-panels and the 1MB
// B-chunk both swizzle designs keep resident (explains why each locality
// partition gained only ~10-30us). xw has zero L2 reuse value (consumed a
// whole kernel later as a 256MB stream), so `nt` is pure pollution removal.
// Coherence unaffected (kernel-boundary visibility).
__global__ __launch_bounds__(256,4) void gemm_xw_kernel(
    const short* __restrict__ A, const short* __restrict__ B,
    const float* __restrict__ bias, short* __restrict__ C)
{
  __shared__ __align__(16) short As[4096];   // [128][32]
  __shared__ __align__(16) short Bs[4096];
  const int tid = threadIdx.x;
  const int bid = (int)blockIdx.x;
  const int c   = bid & 7;            // XCD (round-robin dispatch)
  const int rr  = bid >> 3;           // 0..1023 within XCD
  const int bn  = c*4 + (rr & 3);     // fixed 4-column B set per XCD
  const int bm  = rr >> 2;            // 0..255 (= s index)
  const size_t r0 = (size_t)bm*128, n0 = (size_t)bn*128;
  const int lane = tid & 63, wave = tid >> 6;
  const int wm = (wave>>1)*64, wn = (wave&1)*64;
  const int l15 = lane & 15, quad = lane >> 4;

  f32x4 acc[4][4];
  #pragma unroll
  for (int m=0;m<4;++m)
    #pragma unroll
    for (int n=0;n<4;++n) acc[m][n] = (f32x4)0.0f;

  const int c0 = wave*64 + lane;      // staging slot, rep 0
  const int c1 = c0 + 256;            // rep 1

  for (int kk = 0; kk < 32; ++kk){
    const int k0 = kk*32;
    __syncthreads();   // previous iter's LDS reads done
    // async DMA global -> LDS, 16B per lane, lane-contiguous dest
    __builtin_amdgcn_global_load_lds(
        (const void*)(A + (r0 + (c0>>2))*HID + k0 + (c0&3)*8),
        (void*)((char*)As + wave*1024), 16, 0, 0);
    __builtin_amdgcn_global_load_lds(
        (const void*)(A + (r0 + (c1>>2))*HID + k0 + (c1&3)*8),
        (void*)((char*)As + 4096 + wave*1024), 16, 0, 0);
    __builtin_amdgcn_global_load_lds(
        (const void*)(B + (n0 + (c0>>2))*HID + k0 + (c0&3)*8),
        (void*)((char*)Bs + wave*1024), 16, 0, 0);
    __builtin_amdgcn_global_load_lds(
        (const void*)(B + (n0 + (c1>>2))*HID + k0 + (c1&3)*8),
        (void*)((char*)Bs + 4096 + wave*1024), 16, 0, 0);
    __syncthreads();   // DMA landed (barrier drains vmcnt)
    short8 af[4], bf[4];
    #pragma unroll
    for (int m=0;m<4;++m) af[m] = *(const short8*)(As + (wm + m*16 + l15)*32 + quad*8);
    #pragma unroll
    for (int n=0;n<4;++n) bf[n] = *(const short8*)(Bs + (wn + n*16 + l15)*32 + quad*8);
    #pragma unroll
    for (int m=0;m<4;++m)
      #pragma unroll
      for (int n=0;n<4;++n)
        acc[m][n] = __builtin_amdgcn_mfma_f32_16x16x32_bf16(af[m], bf[n], acc[m][n], 0,0,0);
  }
  // epilogue: pack 4 adjacent bf16 -> 8B NON-TEMPORAL stores (L2 bypass)
  #pragma unroll
  for (int n=0;n<4;++n){
    int s = (int)n0 + wn + n*16;          // start col, multiple of 16
    float bs = bias[s + l15];
    int g = s >> 10, jgi = (s & 1023) >> 4;
    #pragma unroll
    for (int m=0;m<4;++m){
      #pragma unroll
      for (int rg=0; rg<4; ++rg){
        u32 w0 = (u32)(unsigned short)bf16b(acc[m][n][rg] + bs);
        u32 w1 = __shfl_down(w0, 1);
        u32 w2 = __shfl_down(w0, 2);
        u32 w3 = __shfl_down(w0, 3);
        if ((l15 & 3) == 0){
          u64 pk = (u64)w0 | ((u64)w1<<16) | ((u64)w2<<32) | ((u64)w3<<48);
          int rowin = wm + m*16 + quad*4 + rg;    // batch b 0..127
          __builtin_nontemporal_store(pk,
            (u64*)(C + (((size_t)bm*64 + jgi)*128 + rowin)*64 + g*16 + l15));
        }
      }
    }
  }
}

// ---- phase 2: persistent LSTM recurrence -- BYTE-EXACT R1 (962us, banked;
// 0/5 on modifications, 0/4 on fusion attempts). ----
__global__ __launch_bounds__(256,2) void lstm_kernel(
    const short* __restrict__ whh, const short* __restrict__ xw,
    short* __restrict__ h_all, u32* __restrict__ flags)
{
  __shared__ f32x4 part[2][4][4][64];   // [buf][wave][gate][lane] = 32 KB

  const int tid  = threadIdx.x;
  const int lane = tid & 63;
  const int wave = tid >> 6;            // K-slice 0..3 (256 each)
  const int l15  = lane & 15;
  const int quad = lane >> 4;
  const int bg = blockIdx.x & 7;        // batch group
  const int jg = blockIdx.x >> 3;       // 0..63
  const int b0 = bg*16;
  const int j0 = jg*16;
  const int ks0 = wave*256;

  __builtin_amdgcn_fence(__ATOMIC_ACQUIRE, "agent");  // once: clear stale L2

  // Whh slice, MFMA B-fragment layout (no pinning -- rounds 2/3)
  short8 Bf[4][8];
  #pragma unroll
  for (int g=0; g<4; ++g)
    #pragma unroll
    for (int kit=0; kit<8; ++kit)
      Bf[g][kit] = *(const short8*)(whh + (size_t)(g*1024 + j0 + l15)*HID
                                    + ks0 + kit*32 + quad*8);

  u32* fgrp = flags + bg*64;            // one flag per producer block

  // elementwise cell mapping: cell = tid (r 0..15 x jj 0..15)
  const int r  = tid >> 4;
  const int jj = tid & 15;
  const int ln = (r>>2)*16 + jj;        // frag lane of cell
  const int rg = r & 3;                 // frag reg of cell
  float cc = 0.0f;                      // cell state in register

  // prefetch xw for t=0
  short xwc[4];
  {
    const short* xb = xw + (((size_t)0*64 + jg)*128 + b0 + r)*64 + jj;
    #pragma unroll
    for (int g=0; g<4; ++g) xwc[g] = xb[g*16];
  }

  for (int t = 0; t < SQLEN; ++t){
    const short* hin  = h_all + (size_t)t*131072;
    short*       hout = h_all + (size_t)(t+1)*131072;

    // prefetch next step's xw early (independent of h)
    short xwn[4];
    if (t < SQLEN-1){
      const short* xb = xw + (((size_t)(t+1)*64 + jg)*128 + b0 + r)*64 + jj;
      #pragma unroll
      for (int g=0; g<4; ++g) xwn[g] = xb[g*16];
    }

    // per-wave spin: only the 16 producer blocks of THIS wave's K-slice.
    if (t){
      u32* fp = fgrp + wave*16 + l15;
      while (__hip_atomic_load(fp, __ATOMIC_RELAXED,
                               __HIP_MEMORY_SCOPE_AGENT) < (u32)t)
        __builtin_amdgcn_s_sleep(1);
      asm volatile("" ::: "memory");    // no hoist of h loads above the spin
    }

    // h fragments: plain cached coalesced 16B loads (fresh addresses)
    short8 Af[8];
    #pragma unroll
    for (int kit=0; kit<8; ++kit)
      Af[kit] = *(const short8*)(hin + (size_t)(b0 + l15)*HID
                                 + ks0 + kit*32 + quad*8);

    f32x4 acc[4];
    #pragma unroll
    for (int g=0; g<4; ++g) acc[g] = (f32x4)0.0f;
    #pragma unroll
    for (int kit=0; kit<8; ++kit)
      #pragma unroll
      for (int g=0; g<4; ++g)
        acc[g] = __builtin_amdgcn_mfma_f32_16x16x32_bf16(Af[kit], Bf[g][kit], acc[g],0,0,0);

    // single-pass cross-wave reduce, all 4 gates, double-buffered
    const int pb = t & 1;
    #pragma unroll
    for (int g=0; g<4; ++g) part[pb][wave][g][lane] = acc[g];
    __syncthreads();

    float gv[4];
    #pragma unroll
    for (int g=0; g<4; ++g){
      float s = bf2f(xwc[g]);
      #pragma unroll
      for (int w=0; w<4; ++w)
        s += ((const float*)&part[pb][w][g][ln])[rg];
      gv[g] = s;
    }

    float it = sigm(gv[0]), ft = sigm(gv[1]), ch = tanhx(gv[2]), ot = sigm(gv[3]);
    cc = cc*ft + it*ch;
    float hv = ot * tanhx(cc);

    // pack 4 adjacent cells -> one 8B write-through store
    u32 w0 = (u32)(unsigned short)bf16b(hv);
    u32 w1 = __shfl_down(w0, 1);
    u32 w2 = __shfl_down(w0, 2);
    u32 w3 = __shfl_down(w0, 3);
    if (!(tid & 3)){
      u64 hp = (u64)w0 | ((u64)w1<<16) | ((u64)w2<<32) | ((u64)w3<<48);
      __hip_atomic_store((u64*)(hout + (size_t)(b0 + r)*HID + j0 + jj), hp,
                         __ATOMIC_RELAXED, __HIP_MEMORY_SCOPE_AGENT);
    }
    xwc[0]=xwn[0]; xwc[1]=xwn[1]; xwc[2]=xwn[2]; xwc[3]=xwn[3];
    __syncthreads();   // all waves' h stores drained (vmcnt0 at barrier)

    if (t < SQLEN-1 && tid == 0)
      __hip_atomic_store(fgrp + jg, (u32)(t+1), __ATOMIC_RELAXED,
                         __HIP_MEMORY_SCOPE_AGENT);   // plain store, no RMW
  }
}

// ---- phase 3: out[b][c] = h[b]. Wfc[c] + bfc[c], fp32. 256 blocks:
// 32 b-groups x 8 class-slices of 125 (proven). ----
__global__ __launch_bounds__(256) void fc_kernel(const short* __restrict__ h,
    const float* __restrict__ wfc, const float* __restrict__ bfc, float* __restrict__ out)
{
  __shared__ float hs[4][1024];
  int tid = threadIdx.x;
  int b0 = (blockIdx.x >> 3)*4;
  int cs = (blockIdx.x & 7)*125;
  for (int i = tid; i < 4096; i += 256){
    int bb = i >> 10, k = i & 1023;
    hs[bb][k] = bf2f(h[(size_t)(b0+bb)*HID + k]);
  }
  __syncthreads();
  for (int c = cs + tid; c < cs + 125; c += 256){
    const float* w = wfc + (size_t)c*HID;
    float a0=0.f,a1=0.f,a2=0.f,a3=0.f;
    for (int k=0; k<1024; k+=4){
      float4 wv = *(const float4*)(w + k);
      a0 += wv.x*hs[0][k] + wv.y*hs[0][k+1] + wv.z*hs[0][k+2] + wv.w*hs[0][k+3];
      a1 += wv.x*hs[1][k] + wv.y*hs[1][k+1] + wv.z*hs[1][k+2] + wv.w*hs[1][k+3];
      a2 += wv.x*hs[2][k] + wv.y*hs[2][k+1] + wv.z*hs[2][k+2] + wv.w*hs[2][k+3];
      a3 += wv.x*hs[3][k] + wv.y*hs[3][k+1] + wv.z*hs[3][k+2] + wv.w*hs[3][k+3];
    }
    float bb = bfc[c];
    out[(size_t)(b0+0)*NCLS + c] = a0 + bb;
    out[(size_t)(b0+1)*NCLS + c] = a1 + bb;
    out[(size_t)(b0+2)*NCLS + c] = a2 + bb;
    out[(size_t)(b0+3)*NCLS + c] = a3 + bb;
  }
}

extern "C" void kernel_launch(void* const* d_in, const int* in_sizes, int n_in,
                              void* d_out, int out_size, void* d_ws, size_t ws_size,
                              hipStream_t stream) {
  const float* x   = (const float*)d_in[0];
  const float* Wxh = (const float*)d_in[1];
  const float* bxh = (const float*)d_in[2];
  const float* Whh = (const float*)d_in[3];
  const float* bhh = (const float*)d_in[4];
  const float* Wfc = (const float*)d_in[5];
  const float* bfc = (const float*)d_in[6];
  float* out = (float*)d_out;

  char* ws = (char*)d_ws;
  // h_all (257 x 256KB = 64.25MB) ALIASES xbf (64MB): xbf dead after gemm.
  short*    h_all = (short*)(ws + 0);
  short*    xbf   = (short*)(ws + 0);
  short*    wxhb  = (short*)(ws + 68157440);     // 65 MB
  short*    whhb  = (short*)(ws + 76546048);     // 73 MB
  float*    biasg = (float*)(ws + 84934656);     // 81 MB
  short*    xw    = (short*)(ws + 85983232);     // 82 MB, 256 MB gate-blocked
  u32*      flags = (u32*)(ws + 354418688);      // 512 producer flags

  hipMemsetAsync(flags, 0, 4096, stream);

  cast_x_kernel<<<4096, 256, 0, stream>>>(x, xbf);
  cast_prep_kernel<<<8208, 256, 0, stream>>>(Wxh, Whh, bxh, bhh, wxhb, whhb, biasg);
  gemm_xw_kernel<<<8192, 256, 0, stream>>>(xbf, wxhb, biasg, xw);
  // xbf now dead; zero h_all[0] (t=0 input state)
  hipMemsetAsync(ws, 0, 262144, stream);
  lstm_kernel  <<<512,  256, 0, stream>>>(whhb, xw, h_all, flags);
  fc_kernel    <<<256,  256, 0, stream>>>(h_all + (size_t)SQLEN*131072, Wfc, bfc, out);
}